// Round 1
// baseline (133.408 us; speedup 1.0000x reference)
//
#include <hip/hip_runtime.h>

// MultiboxLoss: B=128, P=8732, C=21
//   out[0] = smooth_ex_loss_sum(pos) / n_pos_total
//   out[1] = CE_sum(pos | mined_neg) / n_pos_total
// Mining: top (3*num_pos) negatives by bg_loss per batch row. Since
// 3*num_pos >= (P - num_pos) for this data (labels uniform 0..20), the mined
// set is ALL negatives -> classification = sum of all CE. We decide this per
// row at runtime from the measured num_pos; a general top-k fallback (bit-wise
// binary search on bg_loss keys) covers the other case.

#define B_ 128
#define P_ 8732
#define C_ 21
constexpr int TPB = 256;
constexpr int NPB = (P_ + TPB - 1) / TPB; // 35

__device__ __forceinline__ float waveSumF(float v) {
#pragma unroll
  for (int o = 32; o; o >>= 1) v += __shfl_down(v, o);
  return v;
}
__device__ __forceinline__ int waveSumI(int v) {
#pragma unroll
  for (int o = 32; o; o >>= 1) v += __shfl_down(v, o);
  return v;
}

// ---------------- main streaming kernel ----------------
__global__ __launch_bounds__(TPB) void k_main(
    const float* __restrict__ conf, const float* __restrict__ pred,
    const int* __restrict__ labels, const float* __restrict__ gt,
    double* __restrict__ g, double* __restrict__ ceneg, int* __restrict__ npos) {
  __shared__ __align__(16) float tile[TPB * C_];
  const int b = blockIdx.y;
  const int p0 = blockIdx.x * TPB;
  const int cnt = min(TPB, P_ - p0);
  const int nval = cnt * C_;
  const int tid = threadIdx.x;

  // cooperative float4 tile load (tile starts are 16B aligned: (b*P+p0)*21*4 % 16 == 0)
  const float* src = conf + ((size_t)b * P_ + p0) * C_;
  const int n4 = nval >> 2;
  const float4* s4 = (const float4*)src;
  float4* t4 = (float4*)tile;
  for (int i = tid; i < n4; i += TPB) t4[i] = s4[i];
  for (int i = (n4 << 2) + tid; i < nval; i += TPB) tile[i] = src[i];
  __syncthreads();

  float ce_pos = 0.f, ce_neg = 0.f, sm = 0.f;
  int np = 0;
  if (tid < cnt) {
    const float* row = &tile[tid * C_];
    float m = row[0];
#pragma unroll
    for (int c = 1; c < C_; ++c) m = fmaxf(m, row[c]);
    float s = 0.f;
#pragma unroll
    for (int c = 0; c < C_; ++c) s += __expf(row[c] - m);
    const float lse = m + __logf(s);
    const size_t gp = (size_t)b * P_ + p0 + tid;
    const int lab = labels[gp];
    const float ce = lse - row[lab];
    if (lab > 0) {
      np = 1;
      ce_pos = ce;
      const float4 pr = ((const float4*)pred)[gp];
      const float4 gv = ((const float4*)gt)[gp];
      // smooth-ex loss, BETA=1 ALPHA=2: a = 1/(1-e^-2), c = a - 1.5
      const float A = 1.1565176427496657f;
      const float Cc = -0.3434823572503343f;
      float d;
      d = fabsf(pr.x - gv.x); sm += (d < 1.f) ? A * (d + (__expf(-2.f * d) - 1.f) * 0.5f) : d + Cc;
      d = fabsf(pr.y - gv.y); sm += (d < 1.f) ? A * (d + (__expf(-2.f * d) - 1.f) * 0.5f) : d + Cc;
      d = fabsf(pr.z - gv.z); sm += (d < 1.f) ? A * (d + (__expf(-2.f * d) - 1.f) * 0.5f) : d + Cc;
      d = fabsf(pr.w - gv.w); sm += (d < 1.f) ? A * (d + (__expf(-2.f * d) - 1.f) * 0.5f) : d + Cc;
    } else {
      ce_neg = ce;
    }
  }

  // block reduction (4 waves)
  sm = waveSumF(sm);
  ce_pos = waveSumF(ce_pos);
  ce_neg = waveSumF(ce_neg);
  np = waveSumI(np);
  __shared__ float w0[4], w1[4], w2[4];
  __shared__ int w3[4];
  const int wid = tid >> 6, lane = tid & 63;
  if (lane == 0) { w0[wid] = sm; w1[wid] = ce_pos; w2[wid] = ce_neg; w3[wid] = np; }
  __syncthreads();
  if (tid == 0) {
    float S = 0, CP = 0, CN = 0; int NP = 0;
#pragma unroll
    for (int w = 0; w < TPB / 64; ++w) { S += w0[w]; CP += w1[w]; CN += w2[w]; NP += w3[w]; }
    atomicAdd(&g[0], (double)S);
    atomicAdd(&g[1], (double)CP);
    atomicAdd(&ceneg[b], (double)CN);
    atomicAdd(&npos[b], NP);
  }
}

// ---------------- per-row decision ----------------
__global__ __launch_bounds__(B_) void k_decide(double* __restrict__ g,
                                               const double* __restrict__ ceneg,
                                               const int* __restrict__ npos,
                                               int* __restrict__ flags) {
  const int tid = threadIdx.x; // 128 threads = 2 waves
  const int np = npos[tid];
  const int need = 3 * np;
  const int nav = P_ - np;
  double cn = 0.0;
  int fl = 0;
  if (need >= nav) cn = ceneg[tid]; else fl = 1; // all negatives selected (hot path)
  flags[tid] = fl;
  int n = np;
#pragma unroll
  for (int o = 32; o; o >>= 1) { cn += __shfl_down(cn, o); n += __shfl_down(n, o); }
  __shared__ double sd[2];
  __shared__ int si[2];
  if ((tid & 63) == 0) { sd[tid >> 6] = cn; si[tid >> 6] = n; }
  __syncthreads();
  if (tid == 0) {
    g[2] = sd[0] + sd[1];            // selected-negative CE (easy rows)
    g[3] = (double)(si[0] + si[1]);  // n_pos_total
  }
}

// ---------------- general top-k fallback (never taken for this data) ----------------
__device__ __forceinline__ unsigned keyCE(const float* __restrict__ conf,
                                          const int* __restrict__ labels,
                                          int b, int p, float& ce) {
  const float* row = conf + ((size_t)b * P_ + p) * C_;
  float m = row[0];
  for (int c = 1; c < C_; ++c) m = fmaxf(m, row[c]);
  float s = 0.f;
  for (int c = 0; c < C_; ++c) s += __expf(row[c] - m);
  const float lse = m + __logf(s);
  const int lab = labels[(size_t)b * P_ + p];
  ce = lse - row[lab];
  if (lab > 0) return 0u; // positives excluded
  unsigned u = __float_as_uint(lse - row[0]); // bg_loss -> order-preserving key
  u = (u & 0x80000000u) ? ~u : (u | 0x80000000u);
  return u ? u : 1u;
}

__global__ __launch_bounds__(TPB) void k_fallback(const float* __restrict__ conf,
                                                  const int* __restrict__ labels,
                                                  double* __restrict__ g,
                                                  const int* __restrict__ npos,
                                                  const int* __restrict__ flags) {
  const int b = blockIdx.x;
  if (!flags[b]) return;
  const int tid = threadIdx.x;
  const int need = 3 * npos[b];
  __shared__ int icnt[4];
  __shared__ float fsum[4];

  // binary search: largest key k with count(key >= k) >= need
  unsigned long long lo = 1, hi = 0xFFFFFFFFull, ans = 1;
  while (lo <= hi) {
    const unsigned long long mid = lo + ((hi - lo) >> 1);
    int c = 0;
    float dummy;
    for (int p = tid; p < P_; p += TPB)
      if ((unsigned long long)keyCE(conf, labels, b, p, dummy) >= mid) c++;
    c = waveSumI(c);
    if ((tid & 63) == 0) icnt[tid >> 6] = c;
    __syncthreads();
    const int tot = icnt[0] + icnt[1] + icnt[2] + icnt[3];
    if (tot >= need) { ans = mid; lo = mid + 1; } else { hi = mid - 1; }
    __syncthreads();
  }

  // strictly-greater elements
  int cgt = 0;
  float sgt = 0.f;
  for (int p = tid; p < P_; p += TPB) {
    float ce;
    const unsigned long long k = keyCE(conf, labels, b, p, ce);
    if (k > ans) { cgt++; sgt += ce; }
  }
  cgt = waveSumI(cgt);
  sgt = waveSumF(sgt);
  if ((tid & 63) == 0) { icnt[tid >> 6] = cgt; fsum[tid >> 6] = sgt; }
  __syncthreads();
  if (tid == 0) {
    const int gtot = icnt[0] + icnt[1] + icnt[2] + icnt[3];
    double s = (double)(fsum[0] + fsum[1] + fsum[2] + fsum[3]);
    int r = need - gtot;
    int taken = 0;
    for (int p = 0; p < P_ && taken < r; ++p) { // stable tie-break by index
      float ce;
      if (keyCE(conf, labels, b, p, ce) == ans) { s += ce; taken++; }
    }
    atomicAdd(&g[2], s);
  }
}

// ---------------- finalize ----------------
__global__ void k_final(const double* __restrict__ g, float* __restrict__ out) {
  out[0] = (float)(g[0] / g[3]);
  out[1] = (float)((g[1] + g[2]) / g[3]);
}

extern "C" void kernel_launch(void* const* d_in, const int* in_sizes, int n_in,
                              void* d_out, int out_size, void* d_ws, size_t ws_size,
                              hipStream_t stream) {
  const float* conf = (const float*)d_in[0];
  const float* pred = (const float*)d_in[1];
  const int* labels = (const int*)d_in[2];
  const float* gt = (const float*)d_in[3];
  float* out = (float*)d_out;

  double* g = (double*)d_ws;       // [0]=smooth,[1]=ce_pos,[2]=ce_neg_sel,[3]=n_pos
  double* ceneg = g + 4;           // [B]
  int* npos = (int*)(ceneg + B_);  // [B]
  int* flags = npos + B_;          // [B]
  const size_t zbytes = 4 * sizeof(double) + B_ * sizeof(double) + 2 * B_ * sizeof(int);
  hipMemsetAsync(d_ws, 0, zbytes, stream);

  hipLaunchKernelGGL(k_main, dim3(NPB, B_), dim3(TPB), 0, stream,
                     conf, pred, labels, gt, g, ceneg, npos);
  hipLaunchKernelGGL(k_decide, dim3(1), dim3(B_), 0, stream, g, ceneg, npos, flags);
  hipLaunchKernelGGL(k_fallback, dim3(B_), dim3(TPB), 0, stream, conf, labels, g, npos, flags);
  hipLaunchKernelGGL(k_final, dim3(1), dim3(1), 0, stream, g, out);
}

// Round 2
// 56.749 us; speedup vs baseline: 2.3508x; 2.3508x over previous
//
#include <hip/hip_runtime.h>

// MultiboxLoss: B=128, P=8732, C=21
//   out[0] = smooth_ex_loss_sum(pos) / n_pos_total
//   out[1] = CE_sum(pos | mined_neg) / n_pos_total
// Hot path: 3*num_pos >= #negatives for this data -> mined set = ALL priors.
// R2 change: removed same-address double-CAS atomics (R1: 4480 blocks x 2
// atomicAdd(double) -> CAS-loop serialization, 127us @ 5.9% VALU). Each block
// now writes a private float2 partial slot; tiny reduce kernel sums in double.
// Per-row ceneg/npos use native f32/i32 atomicAdd (35-way, no CAS loop).

#define B_ 128
#define P_ 8732
#define C_ 21
constexpr int TPB = 256;
constexpr int NPB = (P_ + TPB - 1) / TPB; // 35
constexpr int NBLK = NPB * B_;            // 4480

__device__ __forceinline__ float waveSumF(float v) {
#pragma unroll
  for (int o = 32; o; o >>= 1) v += __shfl_down(v, o);
  return v;
}
__device__ __forceinline__ int waveSumI(int v) {
#pragma unroll
  for (int o = 32; o; o >>= 1) v += __shfl_down(v, o);
  return v;
}
__device__ __forceinline__ double waveSumD(double v) {
#pragma unroll
  for (int o = 32; o; o >>= 1) v += __shfl_down(v, o);
  return v;
}

// ---------------- main streaming kernel ----------------
__global__ __launch_bounds__(TPB) void k_main(
    const float* __restrict__ conf, const float* __restrict__ pred,
    const int* __restrict__ labels, const float* __restrict__ gt,
    float2* __restrict__ part, float* __restrict__ ceneg, int* __restrict__ npos) {
  __shared__ __align__(16) float tile[TPB * C_];
  const int b = blockIdx.y;
  const int p0 = blockIdx.x * TPB;
  const int cnt = min(TPB, P_ - p0);
  const int nval = cnt * C_;
  const int tid = threadIdx.x;

  // cooperative float4 tile load (tile start (b*P+p0)*21*4 is 16B-aligned)
  const float* src = conf + ((size_t)b * P_ + p0) * C_;
  const int n4 = nval >> 2;
  const float4* s4 = (const float4*)src;
  float4* t4 = (float4*)tile;
  for (int i = tid; i < n4; i += TPB) t4[i] = s4[i];
  for (int i = (n4 << 2) + tid; i < nval; i += TPB) tile[i] = src[i];
  __syncthreads();

  float ce_pos = 0.f, ce_neg = 0.f, sm = 0.f;
  int np = 0;
  if (tid < cnt) {
    const float* row = &tile[tid * C_];
    float m = row[0];
#pragma unroll
    for (int c = 1; c < C_; ++c) m = fmaxf(m, row[c]);
    float s = 0.f;
#pragma unroll
    for (int c = 0; c < C_; ++c) s += __expf(row[c] - m);
    const float lse = m + __logf(s);
    const size_t gp = (size_t)b * P_ + p0 + tid;
    const int lab = labels[gp];
    const float ce = lse - row[lab];
    if (lab > 0) {
      np = 1;
      ce_pos = ce;
      const float4 pr = ((const float4*)pred)[gp];
      const float4 gv = ((const float4*)gt)[gp];
      // smooth-ex loss, BETA=1 ALPHA=2: a = 1/(1-e^-2), c = a - 1.5
      const float A = 1.1565176427496657f;
      const float Cc = -0.3434823572503343f;
      float d;
      d = fabsf(pr.x - gv.x); sm += (d < 1.f) ? A * (d + (__expf(-2.f * d) - 1.f) * 0.5f) : d + Cc;
      d = fabsf(pr.y - gv.y); sm += (d < 1.f) ? A * (d + (__expf(-2.f * d) - 1.f) * 0.5f) : d + Cc;
      d = fabsf(pr.z - gv.z); sm += (d < 1.f) ? A * (d + (__expf(-2.f * d) - 1.f) * 0.5f) : d + Cc;
      d = fabsf(pr.w - gv.w); sm += (d < 1.f) ? A * (d + (__expf(-2.f * d) - 1.f) * 0.5f) : d + Cc;
    } else {
      ce_neg = ce;
    }
  }

  // block reduction (4 waves)
  sm = waveSumF(sm);
  ce_pos = waveSumF(ce_pos);
  ce_neg = waveSumF(ce_neg);
  np = waveSumI(np);
  __shared__ float w0[4], w1[4], w2[4];
  __shared__ int w3[4];
  const int wid = tid >> 6, lane = tid & 63;
  if (lane == 0) { w0[wid] = sm; w1[wid] = ce_pos; w2[wid] = ce_neg; w3[wid] = np; }
  __syncthreads();
  if (tid == 0) {
    float S = 0, CP = 0, CN = 0; int NP = 0;
#pragma unroll
    for (int w = 0; w < TPB / 64; ++w) { S += w0[w]; CP += w1[w]; CN += w2[w]; NP += w3[w]; }
    part[blockIdx.y * NPB + blockIdx.x] = make_float2(S, CP); // private slot, no atomic
    atomicAdd(&ceneg[b], CN);  // native f32 atomic, 35-way
    atomicAdd(&npos[b], NP);   // native i32 atomic, 35-way
  }
}

// ---------------- reduce partials + per-row decision ----------------
__global__ __launch_bounds__(TPB) void k_decide(double* __restrict__ g,
                                                const float2* __restrict__ part,
                                                const float* __restrict__ ceneg,
                                                const int* __restrict__ npos,
                                                int* __restrict__ flags) {
  const int tid = threadIdx.x;
  const int wid = tid >> 6, lane = tid & 63;
  __shared__ double sd0[4], sd1[4], sd2[4];
  __shared__ int si[4];

  // phase 1: reduce 4480 float2 partials -> g[0], g[1]
  double sm = 0.0, cp = 0.0;
  for (int i = tid; i < NBLK; i += TPB) {
    const float2 v = part[i];
    sm += (double)v.x;
    cp += (double)v.y;
  }
  sm = waveSumD(sm);
  cp = waveSumD(cp);
  if (lane == 0) { sd0[wid] = sm; sd1[wid] = cp; }
  __syncthreads();
  if (tid == 0) {
    g[0] = sd0[0] + sd0[1] + sd0[2] + sd0[3];
    g[1] = sd1[0] + sd1[1] + sd1[2] + sd1[3];
  }
  __syncthreads();

  // phase 2: per-row decision (rows 0..127)
  double cn = 0.0;
  int n = 0;
  if (tid < B_) {
    const int np = npos[tid];
    const int need = 3 * np;
    const int nav = P_ - np;
    int fl = 0;
    if (need >= nav) cn = (double)ceneg[tid]; else fl = 1; // hot: all negatives mined
    flags[tid] = fl;
    n = np;
  }
  cn = waveSumD(cn);
  n = waveSumI(n);
  if (lane == 0) { sd2[wid] = cn; si[wid] = n; }
  __syncthreads();
  if (tid == 0) {
    g[2] = sd2[0] + sd2[1] + sd2[2] + sd2[3]; // selected-negative CE (easy rows)
    g[3] = (double)(si[0] + si[1] + si[2] + si[3]); // n_pos_total
  }
}

// ---------------- general top-k fallback (never taken for this data) ----------------
__device__ __forceinline__ unsigned keyCE(const float* __restrict__ conf,
                                          const int* __restrict__ labels,
                                          int b, int p, float& ce) {
  const float* row = conf + ((size_t)b * P_ + p) * C_;
  float m = row[0];
  for (int c = 1; c < C_; ++c) m = fmaxf(m, row[c]);
  float s = 0.f;
  for (int c = 0; c < C_; ++c) s += __expf(row[c] - m);
  const float lse = m + __logf(s);
  const int lab = labels[(size_t)b * P_ + p];
  ce = lse - row[lab];
  if (lab > 0) return 0u; // positives excluded
  unsigned u = __float_as_uint(lse - row[0]); // bg_loss -> order-preserving key
  u = (u & 0x80000000u) ? ~u : (u | 0x80000000u);
  return u ? u : 1u;
}

__global__ __launch_bounds__(TPB) void k_fallback(const float* __restrict__ conf,
                                                  const int* __restrict__ labels,
                                                  double* __restrict__ g,
                                                  const int* __restrict__ npos,
                                                  const int* __restrict__ flags) {
  const int b = blockIdx.x;
  if (!flags[b]) return;
  const int tid = threadIdx.x;
  const int need = 3 * npos[b];
  __shared__ int icnt[4];
  __shared__ float fsum[4];

  // binary search: largest key k with count(key >= k) >= need
  unsigned long long lo = 1, hi = 0xFFFFFFFFull, ans = 1;
  while (lo <= hi) {
    const unsigned long long mid = lo + ((hi - lo) >> 1);
    int c = 0;
    float dummy;
    for (int p = tid; p < P_; p += TPB)
      if ((unsigned long long)keyCE(conf, labels, b, p, dummy) >= mid) c++;
    c = waveSumI(c);
    if ((tid & 63) == 0) icnt[tid >> 6] = c;
    __syncthreads();
    const int tot = icnt[0] + icnt[1] + icnt[2] + icnt[3];
    if (tot >= need) { ans = mid; lo = mid + 1; } else { hi = mid - 1; }
    __syncthreads();
  }

  int cgt = 0;
  float sgt = 0.f;
  for (int p = tid; p < P_; p += TPB) {
    float ce;
    const unsigned long long k = keyCE(conf, labels, b, p, ce);
    if (k > ans) { cgt++; sgt += ce; }
  }
  cgt = waveSumI(cgt);
  sgt = waveSumF(sgt);
  if ((tid & 63) == 0) { icnt[tid >> 6] = cgt; fsum[tid >> 6] = sgt; }
  __syncthreads();
  if (tid == 0) {
    const int gtot = icnt[0] + icnt[1] + icnt[2] + icnt[3];
    double s = (double)(fsum[0] + fsum[1] + fsum[2] + fsum[3]);
    int r = need - gtot;
    int taken = 0;
    for (int p = 0; p < P_ && taken < r; ++p) { // stable tie-break by index
      float ce;
      if (keyCE(conf, labels, b, p, ce) == ans) { s += ce; taken++; }
    }
    atomicAdd(&g[2], s); // cold path only
  }
}

// ---------------- finalize ----------------
__global__ void k_final(const double* __restrict__ g, float* __restrict__ out) {
  out[0] = (float)(g[0] / g[3]);
  out[1] = (float)((g[1] + g[2]) / g[3]);
}

extern "C" void kernel_launch(void* const* d_in, const int* in_sizes, int n_in,
                              void* d_out, int out_size, void* d_ws, size_t ws_size,
                              hipStream_t stream) {
  const float* conf = (const float*)d_in[0];
  const float* pred = (const float*)d_in[1];
  const int* labels = (const int*)d_in[2];
  const float* gt = (const float*)d_in[3];
  float* out = (float*)d_out;

  // ws layout
  double* g = (double*)d_ws;                // 8 doubles: [0]=smooth [1]=ce_pos [2]=ce_neg_sel [3]=n_pos
  float* ceneg = (float*)(g + 8);           // [B_]
  int* npos = (int*)(ceneg + B_);           // [B_]
  int* flags = npos + B_;                   // [B_] (fully written by k_decide)
  float2* part = (float2*)(flags + B_);     // [NBLK] (fully written by k_main)
  const size_t zbytes = 8 * sizeof(double) + B_ * sizeof(float) + B_ * sizeof(int);
  hipMemsetAsync(d_ws, 0, zbytes, stream);

  hipLaunchKernelGGL(k_main, dim3(NPB, B_), dim3(TPB), 0, stream,
                     conf, pred, labels, gt, part, ceneg, npos);
  hipLaunchKernelGGL(k_decide, dim3(1), dim3(TPB), 0, stream, g, part, ceneg, npos, flags);
  hipLaunchKernelGGL(k_fallback, dim3(B_), dim3(TPB), 0, stream, conf, labels, g, npos, flags);
  hipLaunchKernelGGL(k_final, dim3(1), dim3(1), 0, stream, g, out);
}

// Round 3
// 39.130 us; speedup vs baseline: 3.4094x; 1.4503x over previous
//
#include <hip/hip_runtime.h>
#include <cstdint>

// MultiboxLoss: B=128, P=8732, C=21
//   out[0] = smooth_ex_loss_sum(pos) / n_pos_total
//   out[1] = CE_sum(pos | mined_neg) / n_pos_total
// Hot path: 3*num_pos >= #negatives -> mined set = ALL priors (decided per row
// at runtime; general top-k fallback kept).
// R3: pipelined k_main — 4 tiles/block, double-buffered LDS staged with
// global_load_lds(16B), labels/pred/gt register-prefetched one tile ahead,
// single reduction tail per block (R2 paid exposed load latency + a
// reduction/atomic tail per tile: 54us @ 12.7% VALU, 15.7% HBM).

#define B_ 128
#define P_ 8732
#define C_ 21
constexpr int TPB = 256;
constexpr int TILE = 256;                   // priors per tile
constexpr int TPBATCH = 35;                 // tiles per batch row (34 full + 28)
constexpr int TAILCNT = P_ - (TPBATCH - 1) * TILE;  // 28
constexpr int NTILES = B_ * TPBATCH;        // 4480
constexpr int TPBLK = 4;                    // tiles per block
constexpr int GRID = NTILES / TPBLK;        // 1120
constexpr int TILE_F = TILE * C_;           // 5376 floats = 21504 B
constexpr int NCHUNK = TILE_F * 4 / 1024;   // 21 chunks of 1024 B

typedef const __attribute__((address_space(1))) uint32_t* gas_u32p;
typedef __attribute__((address_space(3))) uint32_t* las_u32p;

__device__ __forceinline__ float waveSumF(float v) {
#pragma unroll
  for (int o = 32; o; o >>= 1) v += __shfl_down(v, o);
  return v;
}
__device__ __forceinline__ int waveSumI(int v) {
#pragma unroll
  for (int o = 32; o; o >>= 1) v += __shfl_down(v, o);
  return v;
}
__device__ __forceinline__ double waveSumD(double v) {
#pragma unroll
  for (int o = 32; o; o >>= 1) v += __shfl_down(v, o);
  return v;
}

// stage one 256-prior tile (21504 B) into LDS: 21 chunks of 1024 B, wave wid
// takes chunks wid, wid+4, ... ; per-lane global source, clamped at buffer end.
__device__ __forceinline__ void stage_tile(const float* __restrict__ src,
                                           float* dst, const char* clampEnd,
                                           int wid, int lane) {
  const char* base = (const char*)src;
  for (int j = wid; j < NCHUNK; j += 4) {
    const char* s = base + j * 1024 + lane * 16;
    if (s > clampEnd) s = clampEnd;  // only triggers on the very last tile
    __builtin_amdgcn_global_load_lds((gas_u32p)s, (las_u32p)(dst + j * 256), 16, 0, 0);
  }
}

// ---------------- main streaming kernel ----------------
__global__ __launch_bounds__(TPB) void k_main(
    const float* __restrict__ conf, const float* __restrict__ pred,
    const int* __restrict__ labels, const float* __restrict__ gt,
    float2* __restrict__ part, float* __restrict__ ceneg, int* __restrict__ npos) {
  __shared__ __align__(16) float tile[2][TILE_F];  // 43008 B double buffer
  const int tid = threadIdx.x;
  const int wid = tid >> 6, lane = tid & 63;
  const int tau0 = blockIdx.x * TPBLK;
  const int b_first = tau0 / TPBATCH;
  const char* clampEnd = (const char*)conf + (size_t)B_ * P_ * C_ * 4 - 16;
  const float4* pred4 = (const float4*)pred;
  const float4* gt4 = (const float4*)gt;

  // ---- prologue: stage tile0 + per-thread register prefetch for tile0
  {
    const int b = tau0 / TPBATCH, x = tau0 - b * TPBATCH;
    stage_tile(conf + ((size_t)b * P_ + x * TILE) * C_, tile[0], clampEnd, wid, lane);
  }
  int lab_r;
  float4 pr_r, gt_r;
  {
    const int b = tau0 / TPBATCH, x = tau0 - b * TPBATCH;
    size_t gp = (size_t)b * P_ + (size_t)x * TILE + tid;
    if (gp > (size_t)B_ * P_ - 1) gp = (size_t)B_ * P_ - 1;
    lab_r = labels[gp];
    pr_r = pred4[gp];
    gt_r = gt4[gp];
  }
  __syncthreads();  // drains vmcnt(0): tile0 + prefetch complete

  float sm_acc = 0.f, cp_acc = 0.f, cn0 = 0.f, cn1 = 0.f;
  int np0 = 0, np1 = 0;

#pragma unroll
  for (int k = 0; k < TPBLK; ++k) {
    const int tau = tau0 + k;
    const int cur = k & 1;

    // ---- issue next tile stage + next register prefetch
    int lab_n = 0;
    float4 pr_n = make_float4(0, 0, 0, 0), gt_n = pr_n;
    if (k + 1 < TPBLK) {
      const int tn = tau + 1;
      const int bn = tn / TPBATCH, xn = tn - bn * TPBATCH;
      stage_tile(conf + ((size_t)bn * P_ + xn * TILE) * C_, tile[cur ^ 1], clampEnd, wid, lane);
      size_t gp = (size_t)bn * P_ + (size_t)xn * TILE + tid;
      if (gp > (size_t)B_ * P_ - 1) gp = (size_t)B_ * P_ - 1;
      lab_n = labels[gp];
      pr_n = pred4[gp];
      gt_n = gt4[gp];
    }

    // ---- compute tile tau from tile[cur] (staged+drained last iteration)
    const int b = tau / TPBATCH, x = tau - b * TPBATCH;
    const int cnt = (x == TPBATCH - 1) ? TAILCNT : TILE;
    if (tid < cnt) {
      const float* row = &tile[cur][tid * C_];
      float m = row[0];
#pragma unroll
      for (int c = 1; c < C_; ++c) m = fmaxf(m, row[c]);
      float s = 0.f;
#pragma unroll
      for (int c = 0; c < C_; ++c) s += __expf(row[c] - m);
      const float lse = m + __logf(s);
      const float ce = lse - row[lab_r];
      float ce_neg = 0.f;
      int np = 0;
      if (lab_r > 0) {
        np = 1;
        cp_acc += ce;
        // smooth-ex loss, BETA=1 ALPHA=2: a = 1/(1-e^-2), c = a - 1.5
        const float A = 1.1565176427496657f;
        const float Cc = -0.3434823572503343f;
        float d;
        d = fabsf(pr_r.x - gt_r.x); sm_acc += (d < 1.f) ? A * (d + (__expf(-2.f * d) - 1.f) * 0.5f) : d + Cc;
        d = fabsf(pr_r.y - gt_r.y); sm_acc += (d < 1.f) ? A * (d + (__expf(-2.f * d) - 1.f) * 0.5f) : d + Cc;
        d = fabsf(pr_r.z - gt_r.z); sm_acc += (d < 1.f) ? A * (d + (__expf(-2.f * d) - 1.f) * 0.5f) : d + Cc;
        d = fabsf(pr_r.w - gt_r.w); sm_acc += (d < 1.f) ? A * (d + (__expf(-2.f * d) - 1.f) * 0.5f) : d + Cc;
      } else {
        ce_neg = ce;
      }
      if (b == b_first) { cn0 += ce_neg; np0 += np; }
      else             { cn1 += ce_neg; np1 += np; }
    }

    __syncthreads();  // vmcnt(0)+lgkmcnt(0)+barrier: next tile staged, buffer reusable
    lab_r = lab_n; pr_r = pr_n; gt_r = gt_n;
  }

  // ---- single block-level reduction tail
  float sm = waveSumF(sm_acc), cp = waveSumF(cp_acc);
  float c0 = waveSumF(cn0), c1 = waveSumF(cn1);
  int n0 = waveSumI(np0), n1 = waveSumI(np1);
  float* red = tile[0];  // reuse LDS (post-barrier)
  int* redi = (int*)red;
  if (lane == 0) {
    red[wid] = sm; red[4 + wid] = cp; red[8 + wid] = c0; red[12 + wid] = c1;
    redi[16 + wid] = n0; redi[20 + wid] = n1;
  }
  __syncthreads();
  if (tid == 0) {
    float SM = 0, CP = 0, C0 = 0, C1 = 0;
    int N0 = 0, N1 = 0;
#pragma unroll
    for (int w = 0; w < 4; ++w) {
      SM += red[w]; CP += red[4 + w]; C0 += red[8 + w]; C1 += red[12 + w];
      N0 += redi[16 + w]; N1 += redi[20 + w];
    }
    part[blockIdx.x] = make_float2(SM, CP);  // private slot, no atomic
    atomicAdd(&ceneg[b_first], C0);
    atomicAdd(&npos[b_first], N0);
    const int b_last = (tau0 + TPBLK - 1) / TPBATCH;
    if (b_last != b_first) {
      atomicAdd(&ceneg[b_last], C1);
      atomicAdd(&npos[b_last], N1);
    }
  }
}

// ---------------- reduce partials + per-row decision ----------------
__global__ __launch_bounds__(TPB) void k_decide(double* __restrict__ g,
                                                const float2* __restrict__ part,
                                                const float* __restrict__ ceneg,
                                                const int* __restrict__ npos,
                                                int* __restrict__ flags) {
  const int tid = threadIdx.x;
  const int wid = tid >> 6, lane = tid & 63;
  __shared__ double sd0[4], sd1[4], sd2[4];
  __shared__ int si[4];

  // phase 1: reduce GRID float2 partials -> g[0], g[1]
  double sm = 0.0, cp = 0.0;
  for (int i = tid; i < GRID; i += TPB) {
    const float2 v = part[i];
    sm += (double)v.x;
    cp += (double)v.y;
  }
  sm = waveSumD(sm);
  cp = waveSumD(cp);
  if (lane == 0) { sd0[wid] = sm; sd1[wid] = cp; }
  __syncthreads();
  if (tid == 0) {
    g[0] = sd0[0] + sd0[1] + sd0[2] + sd0[3];
    g[1] = sd1[0] + sd1[1] + sd1[2] + sd1[3];
  }
  __syncthreads();

  // phase 2: per-row decision (rows 0..127)
  double cn = 0.0;
  int n = 0;
  if (tid < B_) {
    const int np = npos[tid];
    const int need = 3 * np;
    const int nav = P_ - np;
    int fl = 0;
    if (need >= nav) cn = (double)ceneg[tid]; else fl = 1;  // hot: all negs mined
    flags[tid] = fl;
    n = np;
  }
  cn = waveSumD(cn);
  n = waveSumI(n);
  if (lane == 0) { sd2[wid] = cn; si[wid] = n; }
  __syncthreads();
  if (tid == 0) {
    g[2] = sd2[0] + sd2[1] + sd2[2] + sd2[3];        // selected-neg CE (easy rows)
    g[3] = (double)(si[0] + si[1] + si[2] + si[3]);  // n_pos_total
  }
}

// ---------------- general top-k fallback (never taken for this data) ----------------
__device__ __forceinline__ unsigned keyCE(const float* __restrict__ conf,
                                          const int* __restrict__ labels,
                                          int b, int p, float& ce) {
  const float* row = conf + ((size_t)b * P_ + p) * C_;
  float m = row[0];
  for (int c = 1; c < C_; ++c) m = fmaxf(m, row[c]);
  float s = 0.f;
  for (int c = 0; c < C_; ++c) s += __expf(row[c] - m);
  const float lse = m + __logf(s);
  const int lab = labels[(size_t)b * P_ + p];
  ce = lse - row[lab];
  if (lab > 0) return 0u;  // positives excluded
  unsigned u = __float_as_uint(lse - row[0]);  // bg_loss -> order-preserving key
  u = (u & 0x80000000u) ? ~u : (u | 0x80000000u);
  return u ? u : 1u;
}

__global__ __launch_bounds__(TPB) void k_fallback(const float* __restrict__ conf,
                                                  const int* __restrict__ labels,
                                                  double* __restrict__ g,
                                                  const int* __restrict__ npos,
                                                  const int* __restrict__ flags) {
  const int b = blockIdx.x;
  if (!flags[b]) return;
  const int tid = threadIdx.x;
  const int need = 3 * npos[b];
  __shared__ int icnt[4];
  __shared__ float fsum[4];

  // binary search: largest key k with count(key >= k) >= need
  unsigned long long lo = 1, hi = 0xFFFFFFFFull, ans = 1;
  while (lo <= hi) {
    const unsigned long long mid = lo + ((hi - lo) >> 1);
    int c = 0;
    float dummy;
    for (int p = tid; p < P_; p += TPB)
      if ((unsigned long long)keyCE(conf, labels, b, p, dummy) >= mid) c++;
    c = waveSumI(c);
    if ((tid & 63) == 0) icnt[tid >> 6] = c;
    __syncthreads();
    const int tot = icnt[0] + icnt[1] + icnt[2] + icnt[3];
    if (tot >= need) { ans = mid; lo = mid + 1; } else { hi = mid - 1; }
    __syncthreads();
  }

  int cgt = 0;
  float sgt = 0.f;
  for (int p = tid; p < P_; p += TPB) {
    float ce;
    const unsigned long long k = keyCE(conf, labels, b, p, ce);
    if (k > ans) { cgt++; sgt += ce; }
  }
  cgt = waveSumI(cgt);
  sgt = waveSumF(sgt);
  if ((tid & 63) == 0) { icnt[tid >> 6] = cgt; fsum[tid >> 6] = sgt; }
  __syncthreads();
  if (tid == 0) {
    const int gtot = icnt[0] + icnt[1] + icnt[2] + icnt[3];
    double s = (double)(fsum[0] + fsum[1] + fsum[2] + fsum[3]);
    int r = need - gtot;
    int taken = 0;
    for (int p = 0; p < P_ && taken < r; ++p) {  // stable tie-break by index
      float ce;
      if (keyCE(conf, labels, b, p, ce) == ans) { s += ce; taken++; }
    }
    atomicAdd(&g[2], s);  // cold path only
  }
}

// ---------------- finalize ----------------
__global__ void k_final(const double* __restrict__ g, float* __restrict__ out) {
  out[0] = (float)(g[0] / g[3]);
  out[1] = (float)((g[1] + g[2]) / g[3]);
}

extern "C" void kernel_launch(void* const* d_in, const int* in_sizes, int n_in,
                              void* d_out, int out_size, void* d_ws, size_t ws_size,
                              hipStream_t stream) {
  const float* conf = (const float*)d_in[0];
  const float* pred = (const float*)d_in[1];
  const int* labels = (const int*)d_in[2];
  const float* gt = (const float*)d_in[3];
  float* out = (float*)d_out;

  // ws layout
  double* g = (double*)d_ws;             // 8 doubles: [0]=smooth [1]=ce_pos [2]=ce_neg_sel [3]=n_pos
  float* ceneg = (float*)(g + 8);        // [B_]
  int* npos = (int*)(ceneg + B_);        // [B_]
  int* flags = npos + B_;                // [B_] (fully written by k_decide)
  float2* part = (float2*)(flags + B_);  // [GRID] (fully written by k_main)
  const size_t zbytes = 8 * sizeof(double) + B_ * sizeof(float) + B_ * sizeof(int);
  hipMemsetAsync(d_ws, 0, zbytes, stream);

  hipLaunchKernelGGL(k_main, dim3(GRID), dim3(TPB), 0, stream,
                     conf, pred, labels, gt, part, ceneg, npos);
  hipLaunchKernelGGL(k_decide, dim3(1), dim3(TPB), 0, stream, g, part, ceneg, npos, flags);
  hipLaunchKernelGGL(k_fallback, dim3(B_), dim3(TPB), 0, stream, conf, labels, g, npos, flags);
  hipLaunchKernelGGL(k_final, dim3(1), dim3(1), 0, stream, g, out);
}